// Round 17
// baseline (144.885 us; speedup 1.0000x reference)
//
#include <hip/hip_runtime.h>

#define NT 64
#define NB 8192
#define NS 32
#define NF 16
#define DT 0.05f

typedef float f32x4 __attribute__((ext_vector_type(4)));
typedef short s16x8 __attribute__((ext_vector_type(8)));

// trunc-split f32 -> bf16 hi + bf16 lo (v ~= hi + lo, rel err ~2^-17)
__device__ __forceinline__ void bsplit(float v, unsigned short& hi, unsigned short& lo) {
    unsigned int u = __float_as_uint(v);
    hi = (unsigned short)(u >> 16);
    float rest = v - __uint_as_float(u & 0xFFFF0000u);
    lo = (unsigned short)(__float_as_uint(rest) >> 16);
}

__device__ __forceinline__ void split8(const float* p, s16x8& hi, s16x8& lo) {
#pragma unroll
    for (int e = 0; e < 8; ++e) {
        unsigned short hs, ls;
        bsplit(p[e], hs, ls);
        hi[e] = (short)hs;
        lo[e] = (short)ls;
    }
}

// tanh(x) = 1 - 2/(1 + exp2(K x)), K = 2*log2(e).
__device__ __forceinline__ float tanh1(float x) {
    const float K = 2.8853900817779268f;
    float e = __builtin_amdgcn_exp2f(K * x);
    float r = __builtin_amdgcn_rcpf(e + 1.0f);
    return fmaf(-2.0f, r, 1.0f);
}

// R16 post-mortem: 57.5us, VGPR=36 (spills finally gone), but VALUBusy 25% /
// MfmaUtil 6% / occupancy 9% -> chain-latency-bound on the LDS round-trip
// (ds_read ~120cyc + barrier ~200 + 2M bank conflicts) x 126 iterates.
//
// R17: ZERO-EXCHANGE iterate via A-row permutation. The D->B repack existed
// because D gives lane (m,h) states 4h+r while B consumes states 8h..8h+7.
// But the A-operand row order is free: call A places W row rA(i)=8(i>>2)+(i&3)
// in A-slot i, call B rB(i)=rA(i)+4. Then lane (m,h) PRODUCES states
// {8h..8h+3} (call A) and {8h+4..8h+7} (call B) — exactly the states it
// CONSUMES as its B-fragment. Fixed-point loop: bsplit-pack -> 2x3 MFMA
// (independent chains) -> 8 tanh. No LDS, no barrier, no cross-lane ops.
// Same dot products, same k-summation order as R13/R16 -> identical numerics.
// bias/yp/out follow the permutation and stay contiguous: lane (m,h) owns
// states 8h..8h+7 of batch m end-to-end.
// Occupancy drops to 512 waves (0.5/SIMD) — irrelevant: wall = chain latency,
// idle SIMDs cost nothing (R15 proved extra duplicated waves HURT).
__global__ __launch_bounds__(64, 1) void rnes_kernel(
    const float* __restrict__ y0,
    const float* __restrict__ forces,
    const float* __restrict__ W,
    const float* __restrict__ U,
    const float* __restrict__ bias,
    float* __restrict__ out)
{
    const int lane = threadIdx.x;     // block = 1 wave
    const int m    = lane & 15;       // tile col = batch within tile
    const int h    = lane >> 4;       // k-quad; also selects owned states
    const int gb   = blockIdx.x * 16 + m;   // global batch

    // A-row permutation: slot i of call A holds W row rA(i); call B +4.
    const int rA = 8 * (m >> 2) + (m & 3);   // this lane's A-slot row, call A
    const int rB = rA + 4;                   // call B

    // W fragments (constant): A[i=m][k=8h+e] = W[rA|rB][8h+e].
    s16x8 WAh, WAl, WBh, WBl;
    split8(W + rA * NS + 8 * h, WAh, WAl);
    split8(W + rB * NS + 8 * h, WBh, WBl);

    // U fragments, K padded 16->32 (h>=2 lanes: zeros).
    s16x8 UAh = {0,0,0,0,0,0,0,0}, UAl = UAh, UBh = UAh, UBl = UAh;
    if (h < 2) {
        split8(U + rA * NF + 8 * h, UAh, UAl);
        split8(U + rB * NF + 8 * h, UBh, UBl);
    }

    // D layout under the permutation: lane (m,h) owns states 8h..8h+7 of
    // batch m. bias/y_prev/out all contiguous from offset 8h.
    const f32x4 bvA = *(const f32x4*)(bias + 8 * h);
    const f32x4 bvB = *(const f32x4*)(bias + 8 * h + 4);

    const float* yb = y0 + (size_t)gb * NS + 8 * h;
    f32x4 ypA = *(const f32x4*)(yb);
    f32x4 ypB = *(const f32x4*)(yb + 4);
    {
        float* o0 = out + (size_t)gb * NS + 8 * h;
        __builtin_nontemporal_store(ypA, (f32x4*)(o0));
        __builtin_nontemporal_store(ypB, (f32x4*)(o0 + 4));
    }
    f32x4 yppA = ypA, yppB = ypB;

    // forces prefetch: u[gb][8h..8h+7], h<2 only (B-operand of fu).
    const size_t fstep = (size_t)NB * NF;
    const float* fba = forces + (size_t)gb * NF + 8 * h;
    f32x4 un0 = {0.f,0.f,0.f,0.f}, un1 = un0;
    if (h < 2) {
        un0 = __builtin_nontemporal_load((const f32x4*)(fba + fstep));
        un1 = __builtin_nontemporal_load((const f32x4*)(fba + fstep + 4));
    }

    for (int k = 1; k < NT; ++k) {
        // u B-fragments (bf16 hi/lo; zeros for h>=2 = padded K rows).
        s16x8 Buh = {0,0,0,0,0,0,0,0}, Bul = Buh;
        if (h < 2) {
            float uv[8] = {un0[0],un0[1],un0[2],un0[3],un1[0],un1[1],un1[2],un1[3]};
            split8(uv, Buh, Bul);
        }
        // fu = bias + U u (3-term hi/lo chains, permuted rows)
        f32x4 fuA = bvA;
        fuA = __builtin_amdgcn_mfma_f32_16x16x32_bf16(UAl, Buh, fuA, 0, 0, 0);
        fuA = __builtin_amdgcn_mfma_f32_16x16x32_bf16(UAh, Bul, fuA, 0, 0, 0);
        fuA = __builtin_amdgcn_mfma_f32_16x16x32_bf16(UAh, Buh, fuA, 0, 0, 0);
        f32x4 fuB = bvB;
        fuB = __builtin_amdgcn_mfma_f32_16x16x32_bf16(UBl, Buh, fuB, 0, 0, 0);
        fuB = __builtin_amdgcn_mfma_f32_16x16x32_bf16(UBh, Bul, fuB, 0, 0, 0);
        fuB = __builtin_amdgcn_mfma_f32_16x16x32_bf16(UBh, Buh, fuB, 0, 0, 0);

        // prefetch next step's forces
        if (h < 2) {
            int kn = (k + 1 < NT) ? (k + 1) : (NT - 1);
            un0 = __builtin_nontemporal_load((const f32x4*)(fba + (size_t)kn * fstep));
            un1 = __builtin_nontemporal_load((const f32x4*)(fba + (size_t)kn * fstep + 4));
        }

        // predictor: linear extrapolation (R10-validated).
        f32x4 yA = ypA + (ypA - yppA);
        f32x4 yB = ypB + (ypB - yppB);

        // corrector: y <- yp + DT*tanh(W y + fu). PURE LANE-LOCAL:
        // this lane's 8 produced states ARE its B-fragment states.
        auto iterate = [&]() {
            s16x8 Bh, Bl;
            {
                unsigned short hs, ls;
                bsplit(yA[0], hs, ls); Bh[0] = (short)hs; Bl[0] = (short)ls;
                bsplit(yA[1], hs, ls); Bh[1] = (short)hs; Bl[1] = (short)ls;
                bsplit(yA[2], hs, ls); Bh[2] = (short)hs; Bl[2] = (short)ls;
                bsplit(yA[3], hs, ls); Bh[3] = (short)hs; Bl[3] = (short)ls;
                bsplit(yB[0], hs, ls); Bh[4] = (short)hs; Bl[4] = (short)ls;
                bsplit(yB[1], hs, ls); Bh[5] = (short)hs; Bl[5] = (short)ls;
                bsplit(yB[2], hs, ls); Bh[6] = (short)hs; Bl[6] = (short)ls;
                bsplit(yB[3], hs, ls); Bh[7] = (short)hs; Bl[7] = (short)ls;
            }
            // z = W y + fu (3-term chains, order identical to R13/R16)
            f32x4 zA = fuA;
            zA = __builtin_amdgcn_mfma_f32_16x16x32_bf16(WAl, Bh, zA, 0, 0, 0);
            zA = __builtin_amdgcn_mfma_f32_16x16x32_bf16(WAh, Bl, zA, 0, 0, 0);
            zA = __builtin_amdgcn_mfma_f32_16x16x32_bf16(WAh, Bh, zA, 0, 0, 0);
            f32x4 zB = fuB;
            zB = __builtin_amdgcn_mfma_f32_16x16x32_bf16(WBl, Bh, zB, 0, 0, 0);
            zB = __builtin_amdgcn_mfma_f32_16x16x32_bf16(WBh, Bl, zB, 0, 0, 0);
            zB = __builtin_amdgcn_mfma_f32_16x16x32_bf16(WBh, Bh, zB, 0, 0, 0);

#pragma unroll
            for (int r = 0; r < 4; ++r) {
                yA[r] = fmaf(DT, tanh1(zA[r]), ypA[r]);
                yB[r] = fmaf(DT, tanh1(zB[r]), ypB[r]);
            }
        };
        iterate();
        iterate();
        if (k == 1) iterate();   // no extrapolation history at k=1

        yppA = ypA; yppB = ypB;
        ypA = yA;   ypB = yB;

        float* op = out + ((size_t)k * NB + gb) * NS + 8 * h;
        __builtin_nontemporal_store(yA, (f32x4*)(op));
        __builtin_nontemporal_store(yB, (f32x4*)(op + 4));
    }
}

extern "C" void kernel_launch(void* const* d_in, const int* in_sizes, int n_in,
                              void* d_out, int out_size, void* d_ws, size_t ws_size,
                              hipStream_t stream) {
    const float* y0     = (const float*)d_in[0];
    const float* forces = (const float*)d_in[1];
    const float* W      = (const float*)d_in[2];
    const float* U      = (const float*)d_in[3];
    const float* b      = (const float*)d_in[4];
    float* out = (float*)d_out;

    dim3 grid(NB / 16);   // 512 blocks x 1 wave x 16 batches = 8192
    dim3 block(64);
    rnes_kernel<<<grid, block, 0, stream>>>(y0, forces, W, U, b, out);
}